// Round 1
// 3384.937 us; speedup vs baseline: 2.9757x; 2.9757x over previous
//
#include <hip/hip_runtime.h>
#include <hip/hip_bf16.h>
#include <math.h>
#include <type_traits>

// Problem constants
#define LAY 12
#define DIM 768
#define NH  12
#define FF  3072
#define VOC 32000
#define DK  64
#define BB  2
#define TT  1024
#define NT  (BB*TT)      // 2048 token rows
#define LN_EPS 1e-5f

typedef __hip_bfloat16 bf16;
typedef __attribute__((ext_vector_type(8))) short short8;   // 8 x bf16 (4 VGPRs)
typedef __attribute__((ext_vector_type(4))) float f32x4;

#define GLOAD_LDS16(gp, lp) __builtin_amdgcn_global_load_lds( \
    (const __attribute__((address_space(1))) void*)(gp),      \
    (__attribute__((address_space(3))) void*)(lp), 16, 0, 0)

// ---------------- block reduction helpers (256 threads = 4 waves) -------------
__device__ __forceinline__ float block_sum(float v, float* scratch) {
  #pragma unroll
  for (int o = 32; o > 0; o >>= 1) v += __shfl_down(v, o, 64);
  int lane = threadIdx.x & 63;
  int w = threadIdx.x >> 6;
  __syncthreads();
  if (lane == 0) scratch[w] = v;
  __syncthreads();
  return scratch[0] + scratch[1] + scratch[2] + scratch[3];
}

__device__ __forceinline__ float block_max(float v, float* scratch) {
  #pragma unroll
  for (int o = 32; o > 0; o >>= 1) v = fmaxf(v, __shfl_down(v, o, 64));
  int lane = threadIdx.x & 63;
  int w = threadIdx.x >> 6;
  __syncthreads();
  if (lane == 0) scratch[w] = v;
  __syncthreads();
  return fmaxf(fmaxf(scratch[0], scratch[1]), fmaxf(scratch[2], scratch[3]));
}

// ---------------- embedding ---------------------------------------------------
__global__ __launch_bounds__(256) void embed_kernel(
    const int* __restrict__ tokens, const float* __restrict__ emb,
    const float* __restrict__ pos, float* __restrict__ x) {
  int total = NT * DIM;
  for (int idx = blockIdx.x * 256 + threadIdx.x; idx < total; idx += gridDim.x * 256) {
    int row = idx / DIM;
    int d   = idx - row * DIM;
    int t   = row & (TT - 1);
    int tok = tokens[row];
    x[idx] = emb[(size_t)tok * DIM + d] + pos[(size_t)t * DIM + d];
  }
}

// ---------------- layernorm: one block per row, templated output dtype -------
template<typename OT>
__global__ __launch_bounds__(256) void ln_kernel(
    const float* __restrict__ x, const float* __restrict__ w,
    const float* __restrict__ b, OT* __restrict__ out) {
  __shared__ float scratch[4];
  int row = blockIdx.x;
  const float* xr = x + (size_t)row * DIM;
  float s = 0.f;
  for (int i = threadIdx.x; i < DIM; i += 256) s += xr[i];
  float mean = block_sum(s, scratch) * (1.0f / DIM);
  float vs = 0.f;
  for (int i = threadIdx.x; i < DIM; i += 256) { float d = xr[i] - mean; vs += d * d; }
  float var = block_sum(vs, scratch) * (1.0f / DIM);
  float inv = rsqrtf(var + LN_EPS);
  OT* orow = out + (size_t)row * DIM;
  for (int i = threadIdx.x; i < DIM; i += 256) {
    float v = (xr[i] - mean) * inv * w[i] + b[i];
    if constexpr (std::is_same<OT, float>::value) orow[i] = v;
    else orow[i] = __float2bfloat16(v);
  }
}

// ---------------- weight transpose + fp32->bf16:  W[K,N] -> Wt[N,K] ----------
__global__ __launch_bounds__(256) void transpose_cvt_kernel(
    const float* __restrict__ W, bf16* __restrict__ Wt, int K, int N) {
  __shared__ float tile[64][65];
  int n0 = blockIdx.x * 64, k0 = blockIdx.y * 64;
  int t = threadIdx.x;
  int tr = t >> 4, tc = t & 15;
  #pragma unroll
  for (int p = 0; p < 4; p++) {
    int k = p * 16 + tr;
    float4 v = *(const float4*)&W[(size_t)(k0 + k) * N + n0 + tc * 4];
    tile[tc * 4 + 0][k] = v.x;
    tile[tc * 4 + 1][k] = v.y;
    tile[tc * 4 + 2][k] = v.z;
    tile[tc * 4 + 3][k] = v.w;
  }
  __syncthreads();
  int tn = t >> 2, tk = t & 3;
  alignas(16) bf16 ov[16];
  #pragma unroll
  for (int i = 0; i < 16; i++) ov[i] = __float2bfloat16(tile[tn][tk * 16 + i]);
  bf16* dst = Wt + (size_t)(n0 + tn) * K + k0 + tk * 16;
  *(uint4*)dst = *(uint4*)&ov[0];
  *(uint4*)(dst + 8) = *(uint4*)&ov[8];
}

// ---------------- elementwise fp32 -> bf16 (for emb head weight) -------------
__global__ __launch_bounds__(256) void cvt_bf16_kernel(
    const float* __restrict__ in, bf16* __restrict__ out, int n4) {
  for (int i = blockIdx.x * 256 + threadIdx.x; i < n4; i += gridDim.x * 256) {
    float4 v = *(const float4*)&in[(size_t)i * 4];
    alignas(8) bf16 o[4];
    o[0] = __float2bfloat16(v.x); o[1] = __float2bfloat16(v.y);
    o[2] = __float2bfloat16(v.z); o[3] = __float2bfloat16(v.w);
    *(uint2*)&out[(size_t)i * 4] = *(uint2*)o;
  }
}

// ---------------- bf16 MFMA GEMM (m97 structure) ------------------------------
// C[M,N] = act(A[M,K] @ Bt^T + bias) (+res).  A:[M,K] bf16, Bt:[N,K] bf16.
// 128x128 tile, BK=32, 256 threads = 4 waves in 2x2, each wave 64x64 via
// 4x4 grid of 16x16x32 MFMAs. M%128==0, N%128==0, K%32==0 guaranteed.
template<int ACT, bool RES, bool OBF>
__global__ __launch_bounds__(256) void mfma_gemm(
    const bf16* __restrict__ A, const bf16* __restrict__ Bt,
    const float* __restrict__ bias, const float* __restrict__ res,
    void* __restrict__ Cout, int M, int N, int K) {
  __shared__ bf16 As[128 * 32];
  __shared__ bf16 Bs[128 * 32];
  const int tid = threadIdx.x;
  const int lane = tid & 63;
  const int wave = tid >> 6;
  const int bm = blockIdx.y * 128, bn = blockIdx.x * 128;
  const int wm = (wave >> 1) * 64, wn = (wave & 1) * 64;
  const int l15 = lane & 15, l16 = lane >> 4;

  f32x4 acc[4][4] = {};

  // staging: chunk c in [0,512): row=c>>2 (tile row), seg=c&3 (16B within 64B row)
  const int c0 = tid, c1 = tid + 256;
  const int r0 = c0 >> 2, s0 = c0 & 3;
  const int r1 = c1 >> 2, s1 = c1 & 3;
  const bf16* Ag0 = A + (size_t)(bm + r0) * K + s0 * 8;
  const bf16* Ag1 = A + (size_t)(bm + r1) * K + s1 * 8;
  const bf16* Bg0 = Bt + (size_t)(bn + r0) * K + s0 * 8;
  const bf16* Bg1 = Bt + (size_t)(bn + r1) * K + s1 * 8;
  bf16* Al0 = As + c0 * 8; bf16* Al1 = As + c1 * 8;
  bf16* Bl0 = Bs + c0 * 8; bf16* Bl1 = Bs + c1 * 8;

  for (int k0 = 0; k0 < K; k0 += 32) {
    GLOAD_LDS16(Ag0 + k0, Al0);
    GLOAD_LDS16(Ag1 + k0, Al1);
    GLOAD_LDS16(Bg0 + k0, Bl0);
    GLOAD_LDS16(Bg1 + k0, Bl1);
    __syncthreads();
    short8 af[4], bfr[4];
    #pragma unroll
    for (int i = 0; i < 4; i++)
      af[i] = *(const short8*)(As + (size_t)(wm + i * 16 + l15) * 32 + l16 * 8);
    #pragma unroll
    for (int j = 0; j < 4; j++)
      bfr[j] = *(const short8*)(Bs + (size_t)(wn + j * 16 + l15) * 32 + l16 * 8);
    #pragma unroll
    for (int i = 0; i < 4; i++)
      #pragma unroll
      for (int j = 0; j < 4; j++)
        acc[i][j] = __builtin_amdgcn_mfma_f32_16x16x32_bf16(af[i], bfr[j], acc[i][j], 0, 0, 0);
    __syncthreads();
  }

  // epilogue: C/D layout col=lane&15, row=(lane>>4)*4+reg
  float* Cf = (float*)Cout;
  bf16*  Cb = (bf16*)Cout;
  #pragma unroll
  for (int j = 0; j < 4; j++) {
    int gn = bn + wn + j * 16 + l15;
    float bv = bias ? bias[gn] : 0.f;
    #pragma unroll
    for (int i = 0; i < 4; i++) {
      #pragma unroll
      for (int r = 0; r < 4; r++) {
        int gm = bm + wm + i * 16 + l16 * 4 + r;
        float v = acc[i][j][r] + bv;
        if (ACT == 1) v = 0.5f * v * (1.0f + erff(v * 0.70710678118654752f));
        size_t off = (size_t)gm * N + gn;
        if (RES) v += res[off];
        if (OBF) Cb[off] = __float2bfloat16(v);
        else     Cf[off] = v;
      }
    }
  }
}

// ---------------- flash attention (bf16 MFMA) ---------------------------------
// qkv: [B, T, 3*DIM] bf16, per row: [q | k | v], head h at offset h*DK.
// Grid: (TT/64) x (BB*NH).  Block: 256 = 4 waves; wave w owns q rows
// [q0 + 16w, q0 + 16w + 16).  KV iterated in 64-row tiles with online softmax.
// MFMA 16x16x32: A-frag lane l holds A[row=l&15, k=(l>>4)*8+j];
// C/D layout col=lane&15, row=(lane>>4)*4+reg.
__global__ __launch_bounds__(256) void flash_attn_kernel(
    const bf16* __restrict__ qkv, bf16* __restrict__ y) {
  // V^T tile, XOR-swizzled: element (d, kv) at byte d*128 + ((kv*2) ^ ((d&7)<<4))
  __shared__ alignas(16) char VtRaw[64 * 128];
  // per-wave P tile [16 q][64 kv], row stride 72 elems (+8 pad -> 2-way free)
  __shared__ alignas(16) bf16 Pl[4][16 * 72];

  const int qt = blockIdx.x;
  const int b  = blockIdx.y / NH;
  const int h  = blockIdx.y % NH;
  const int q0 = qt * 64;
  const int tid = threadIdx.x;
  const int lane = tid & 63;
  const int wave = tid >> 6;
  const int l15 = lane & 15, l16 = lane >> 4;

  const bf16* base = qkv + (size_t)b * TT * 3 * DIM;

  // Q fragments held in registers (d split into two 32-chunks)
  short8 qf[2];
  {
    const bf16* qp = base + (size_t)(q0 + wave * 16 + l15) * 3 * DIM + h * DK;
    qf[0] = *(const short8*)(qp + l16 * 8);
    qf[1] = *(const short8*)(qp + 32 + l16 * 8);
  }

  f32x4 oacc[4] = {};            // O[16 q][64 d]: 4 d-tiles of 16
  float mrow[4], lrow[4];        // online-softmax state, rows = l16*4 + r
  #pragma unroll
  for (int r = 0; r < 4; r++) { mrow[r] = -INFINITY; lrow[r] = 0.f; }

  const int skv = tid >> 2;          // staging: kv row 0..63
  const int sd0 = (tid & 3) * 16;    // staging: d chunk of 16
  char* vb = (char*)VtRaw;
  const bf16* kbase = base + DIM + h * DK;
  const bf16* vbase = base + 2 * DIM + h * DK;

  for (int kv0 = 0; kv0 <= q0; kv0 += 64) {
    const bool diag = (kv0 == q0);
    __syncthreads();   // previous PV reads of Vt done before restage

    // ---- stage V^T into LDS (coalesced global read, swizzled scatter) ----
    {
      const bf16* vr = vbase + (size_t)(kv0 + skv) * 3 * DIM + sd0;
      short8 v0 = *(const short8*)vr;
      short8 v1 = *(const short8*)(vr + 8);
      #pragma unroll
      for (int i = 0; i < 8; i++) {
        *(short*)(vb + (sd0 + i) * 128 + ((skv * 2) ^ ((i & 7) << 4))) = v0[i];
        *(short*)(vb + (sd0 + 8 + i) * 128 + ((skv * 2) ^ ((i & 7) << 4))) = v1[i];
      }
    }

    // ---- S = (Q K^T) * scale for 4 kv sub-tiles of 16 ----
    float sv[4][4];
    #pragma unroll
    for (int j = 0; j < 4; j++) {
      if (diag && j > wave) {          // fully-masked sub-tile: skip MFMAs
        #pragma unroll
        for (int r = 0; r < 4; r++) sv[j][r] = -INFINITY;
        continue;
      }
      const bf16* kp = kbase + (size_t)(kv0 + j * 16 + l15) * 3 * DIM;
      short8 kf0 = *(const short8*)(kp + l16 * 8);
      short8 kf1 = *(const short8*)(kp + 32 + l16 * 8);
      f32x4 s = {};
      s = __builtin_amdgcn_mfma_f32_16x16x32_bf16(qf[0], kf0, s, 0, 0, 0);
      s = __builtin_amdgcn_mfma_f32_16x16x32_bf16(qf[1], kf1, s, 0, 0, 0);
      #pragma unroll
      for (int r = 0; r < 4; r++) {
        float v = s[r] * 0.125f;
        // diagonal tile: mask kv_local > q_local  (j==wave here)
        if (diag && j == wave && l15 > l16 * 4 + r) v = -INFINITY;
        sv[j][r] = v;
      }
    }

    // ---- online softmax (row-reduce across the 16 lanes of each group) ----
    float tm[4];
    #pragma unroll
    for (int r = 0; r < 4; r++)
      tm[r] = fmaxf(fmaxf(sv[0][r], sv[1][r]), fmaxf(sv[2][r], sv[3][r]));
    #pragma unroll
    for (int m = 1; m < 16; m <<= 1)
      #pragma unroll
      for (int r = 0; r < 4; r++)
        tm[r] = fmaxf(tm[r], __shfl_xor(tm[r], m, 64));

    float p[4][4], rs[4];
    #pragma unroll
    for (int r = 0; r < 4; r++) {
      float mn = fmaxf(mrow[r], tm[r]);
      float sc = __expf(mrow[r] - mn);   // exp(-inf)=0 on first tile
      mrow[r] = mn;
      lrow[r] *= sc;
      #pragma unroll
      for (int dt = 0; dt < 4; dt++) oacc[dt][r] *= sc;
      rs[r] = 0.f;
      #pragma unroll
      for (int j = 0; j < 4; j++) { p[j][r] = __expf(sv[j][r] - mn); rs[r] += p[j][r]; }
    }
    #pragma unroll
    for (int m = 1; m < 16; m <<= 1)
      #pragma unroll
      for (int r = 0; r < 4; r++)
        rs[r] += __shfl_xor(rs[r], m, 64);
    #pragma unroll
    for (int r = 0; r < 4; r++) lrow[r] += rs[r];

    // ---- P -> bf16 in per-wave LDS (transpose to A-fragment layout) ----
    #pragma unroll
    for (int j = 0; j < 4; j++)
      #pragma unroll
      for (int r = 0; r < 4; r++)
        Pl[wave][(l16 * 4 + r) * 72 + j * 16 + l15] = __float2bfloat16(p[j][r]);

    __syncthreads();   // Vt staged; (also orders per-wave P write->read)

    // ---- O += P @ V ----
    #pragma unroll
    for (int c = 0; c < 2; c++) {
      if (diag && c * 32 > wave * 16 + 15) continue;   // fully-masked kv chunk
      short8 pa = *(const short8*)&Pl[wave][l15 * 72 + c * 32 + l16 * 8];
      #pragma unroll
      for (int dt = 0; dt < 4; dt++) {
        int d = dt * 16 + l15;
        short8 vf = *(const short8*)(vb + d * 128 +
                       ((c * 64 + l16 * 16) ^ ((l15 & 7) << 4)));
        oacc[dt] = __builtin_amdgcn_mfma_f32_16x16x32_bf16(pa, vf, oacc[dt], 0, 0, 0);
      }
    }
  }

  // ---- epilogue: O /= l, write bf16 ----
  float inv[4];
  #pragma unroll
  for (int r = 0; r < 4; r++) inv[r] = 1.0f / lrow[r];
  bf16* yo = y + ((size_t)b * TT + q0 + wave * 16) * DIM + h * DK;
  #pragma unroll
  for (int dt = 0; dt < 4; dt++)
    #pragma unroll
    for (int r = 0; r < 4; r++)
      yo[(size_t)(l16 * 4 + r) * DIM + dt * 16 + l15] =
          __float2bfloat16(oacc[dt][r] * inv[r]);
}

// ---------------- attention: one block per (b, h, q)  (fallback path) --------
template<typename OT>
__global__ __launch_bounds__(256) void attn_kernel(
    const float* __restrict__ qkv, OT* __restrict__ y) {
  __shared__ float sq[DK];
  __shared__ float sc[TT];
  __shared__ float scratch[4];
  __shared__ float osum[4][DK];

  int idx = blockIdx.x;
  int q = idx & (TT - 1); idx >>= 10;
  int h = idx % NH;
  int b = idx / NH;
  int tid = threadIdx.x;

  const float* base = qkv + (size_t)b * TT * 3 * DIM;
  const float* qrow = base + (size_t)q * 3 * DIM + h * DK;
  const float* Kb = base + DIM + h * DK;
  const float* Vb = base + 2 * DIM + h * DK;

  if (tid < DK) sq[tid] = qrow[tid];
  __syncthreads();

  int nk = q + 1;
  float lmax = -INFINITY;
  for (int k = tid; k < nk; k += 256) {
    const float* Kr = Kb + (size_t)k * 3 * DIM;
    float acc = 0.f;
    #pragma unroll
    for (int d = 0; d < DK; d += 4) {
      float4 kv = *(const float4*)(Kr + d);
      acc = fmaf(sq[d], kv.x, acc);
      acc = fmaf(sq[d + 1], kv.y, acc);
      acc = fmaf(sq[d + 2], kv.z, acc);
      acc = fmaf(sq[d + 3], kv.w, acc);
    }
    acc *= 0.125f;
    sc[k] = acc;
    lmax = fmaxf(lmax, acc);
  }
  float gmax = block_max(lmax, scratch);

  float lsum = 0.f;
  for (int k = tid; k < nk; k += 256) {
    float e = __expf(sc[k] - gmax);
    sc[k] = e;
    lsum += e;
  }
  float gsum = block_sum(lsum, scratch);
  float invs = 1.0f / gsum;
  __syncthreads();

  int d = tid & (DK - 1);
  int g = tid >> 6;
  float acc = 0.f;
  for (int k = g; k < nk; k += 4)
    acc = fmaf(sc[k], Vb[(size_t)k * 3 * DIM + d], acc);
  osum[g][d] = acc;
  __syncthreads();
  if (g == 0) {
    float o = (osum[0][d] + osum[1][d] + osum[2][d] + osum[3][d]) * invs;
    size_t off = ((size_t)b * TT + q) * DIM + h * DK + d;
    if constexpr (std::is_same<OT, float>::value) y[off] = o;
    else y[off] = __float2bfloat16(o);
  }
}

// ---------------- fallback fp32 tiled GEMM (round-1 path) --------------------
#define BM 64
#define BN 64
#define BKT 16
template<int ACT, bool BT, bool RES>
__global__ __launch_bounds__(256) void gemm_kernel(
    const float* __restrict__ A, const float* __restrict__ B,
    const float* __restrict__ bias, const float* __restrict__ res,
    float* __restrict__ C, int M, int N, int K) {
  __shared__ float Asl[BKT][BM + 4];
  __shared__ float Bsl[BKT][BN + 4];
  int tid = threadIdx.x;
  int bm = blockIdx.y * BM;
  int bn = blockIdx.x * BN;
  int tx = tid & 15;
  int ty = tid >> 4;
  float acc[4][4] = {};

  for (int k0 = 0; k0 < K; k0 += BKT) {
    #pragma unroll
    for (int i = 0; i < 4; i++) {
      int e = tid + i * 256;
      int m = e >> 4, k = e & 15;
      Asl[k][m] = A[(size_t)(bm + m) * K + k0 + k];
    }
    if (!BT) {
      #pragma unroll
      for (int i = 0; i < 4; i++) {
        int e = tid + i * 256;
        int k = e >> 6, n = e & 63;
        Bsl[k][n] = B[(size_t)(k0 + k) * N + bn + n];
      }
    } else {
      #pragma unroll
      for (int i = 0; i < 4; i++) {
        int e = tid + i * 256;
        int n = e >> 4, k = e & 15;
        Bsl[k][n] = B[(size_t)(bn + n) * K + k0 + k];
      }
    }
    __syncthreads();
    #pragma unroll
    for (int kk = 0; kk < BKT; kk++) {
      float4 av = *(const float4*)&Asl[kk][ty * 4];
      float4 bv = *(const float4*)&Bsl[kk][tx * 4];
      float a[4] = {av.x, av.y, av.z, av.w};
      float bb[4] = {bv.x, bv.y, bv.z, bv.w};
      #pragma unroll
      for (int i = 0; i < 4; i++)
        #pragma unroll
        for (int j = 0; j < 4; j++)
          acc[i][j] = fmaf(a[i], bb[j], acc[i][j]);
    }
    __syncthreads();
  }

  #pragma unroll
  for (int i = 0; i < 4; i++) {
    int m = bm + ty * 4 + i;
    size_t rowoff = (size_t)m * N + bn + tx * 4;
    float4 o;
    float* po = &o.x;
    #pragma unroll
    for (int j = 0; j < 4; j++) {
      float v = acc[i][j];
      if (bias) v += bias[bn + tx * 4 + j];
      if (ACT == 1) v = 0.5f * v * (1.0f + erff(v * 0.70710678118654752f));
      if (RES) v += res[rowoff + j];
      po[j] = v;
    }
    *(float4*)&C[rowoff] = o;
  }
}

// ---------------- driver ------------------------------------------------------
extern "C" void kernel_launch(void* const* d_in, const int* in_sizes, int n_in,
                              void* d_out, int out_size, void* d_ws, size_t ws_size,
                              hipStream_t stream) {
  const int*   tokens = (const int*)d_in[0];
  const float* emb    = (const float*)d_in[1];
  const float* pos    = (const float*)d_in[2];
  const float* ln1_w  = (const float*)d_in[3];
  const float* ln1_b  = (const float*)d_in[4];
  const float* qkv_w  = (const float*)d_in[5];
  const float* qkv_b  = (const float*)d_in[6];
  const float* proj_w = (const float*)d_in[7];
  const float* proj_b = (const float*)d_in[8];
  const float* ln2_w  = (const float*)d_in[9];
  const float* ln2_b  = (const float*)d_in[10];
  const float* ff1_w  = (const float*)d_in[11];
  const float* ff1_b  = (const float*)d_in[12];
  const float* ff2_w  = (const float*)d_in[13];
  const float* ff2_b  = (const float*)d_in[14];
  const float* lnf_w  = (const float*)d_in[15];
  const float* lnf_b  = (const float*)d_in[16];
  float* out = (float*)d_out;

  // ---- bf16 MFMA path workspace layout ----
  const size_t need =
      (size_t)NT * DIM * 4      // x (fp32 residual stream)
    + (size_t)NT * 3 * DIM * 2  // qkv bf16
    + (size_t)NT * DIM * 2      // hb  (LN out, bf16)
    + (size_t)NT * DIM * 2      // yb  (attn out, bf16)
    + (size_t)NT * FF * 2       // ffhb (gelu out, bf16)
    + (size_t)3 * DIM * DIM * 2 // wq  [2304][768]
    + (size_t)DIM * DIM * 2     // wp  [768][768]
    + (size_t)DIM * FF * 2      // wf1 [3072][768]
    + (size_t)FF * DIM * 2      // wf2 [768][3072]
    + (size_t)VOC * DIM * 2;    // embb [32000][768]

  if (ws_size >= need) {
    char* p = (char*)d_ws;
    float* x    = (float*)p;  p += (size_t)NT * DIM * 4;
    bf16* qkvb  = (bf16*)p;   p += (size_t)NT * 3 * DIM * 2;
    bf16* hb    = (bf16*)p;   p += (size_t)NT * DIM * 2;
    bf16* yb    = (bf16*)p;   p += (size_t)NT * DIM * 2;
    bf16* ffhb  = (bf16*)p;   p += (size_t)NT * FF * 2;
    bf16* wq    = (bf16*)p;   p += (size_t)3 * DIM * DIM * 2;
    bf16* wp    = (bf16*)p;   p += (size_t)DIM * DIM * 2;
    bf16* wf1   = (bf16*)p;   p += (size_t)DIM * FF * 2;
    bf16* wf2   = (bf16*)p;   p += (size_t)FF * DIM * 2;
    bf16* embb  = (bf16*)p;   p += (size_t)VOC * DIM * 2;

    embed_kernel<<<1024, 256, 0, stream>>>(tokens, emb, pos, x);
    cvt_bf16_kernel<<<2048, 256, 0, stream>>>(emb, embb, VOC * DIM / 4);

    for (int l = 0; l < LAY; l++) {
      // stage this layer's weights as bf16 [N,K]
      transpose_cvt_kernel<<<dim3(3 * DIM / 64, DIM / 64), 256, 0, stream>>>(
          qkv_w + (size_t)l * DIM * 3 * DIM, wq, DIM, 3 * DIM);
      transpose_cvt_kernel<<<dim3(DIM / 64, DIM / 64), 256, 0, stream>>>(
          proj_w + (size_t)l * DIM * DIM, wp, DIM, DIM);
      transpose_cvt_kernel<<<dim3(FF / 64, DIM / 64), 256, 0, stream>>>(
          ff1_w + (size_t)l * DIM * FF, wf1, DIM, FF);
      transpose_cvt_kernel<<<dim3(DIM / 64, FF / 64), 256, 0, stream>>>(
          ff2_w + (size_t)l * FF * DIM, wf2, FF, DIM);

      ln_kernel<bf16><<<NT, 256, 0, stream>>>(x, ln1_w + l * DIM, ln1_b + l * DIM, hb);

      mfma_gemm<0, false, true><<<dim3(3 * DIM / 128, NT / 128), 256, 0, stream>>>(
          hb, wq, qkv_b + (size_t)l * 3 * DIM, nullptr, qkvb, NT, 3 * DIM, DIM);

      flash_attn_kernel<<<dim3(TT / 64, BB * NH), 256, 0, stream>>>(qkvb, yb);

      mfma_gemm<0, true, false><<<dim3(DIM / 128, NT / 128), 256, 0, stream>>>(
          yb, wp, proj_b + (size_t)l * DIM, x, x, NT, DIM, DIM);

      ln_kernel<bf16><<<NT, 256, 0, stream>>>(x, ln2_w + l * DIM, ln2_b + l * DIM, hb);

      mfma_gemm<1, false, true><<<dim3(FF / 128, NT / 128), 256, 0, stream>>>(
          hb, wf1, ff1_b + (size_t)l * FF, nullptr, ffhb, NT, FF, DIM);

      mfma_gemm<0, true, false><<<dim3(DIM / 128, NT / 128), 256, 0, stream>>>(
          ffhb, wf2, ff2_b + (size_t)l * DIM, x, x, NT, DIM, FF);
    }

    ln_kernel<bf16><<<NT, 256, 0, stream>>>(x, lnf_w, lnf_b, hb);

    mfma_gemm<0, false, false><<<dim3(VOC / 128, NT / 128), 256, 0, stream>>>(
        hb, embb, nullptr, nullptr, out, NT, VOC, DIM);
    return;
  }

  // ---- fallback: round-1 fp32 path ----
  float* x   = (float*)d_ws;
  float* h   = x   + (size_t)NT * DIM;
  float* qkv = h   + (size_t)NT * DIM;
  float* y   = qkv + (size_t)NT * 3 * DIM;
  float* ffh = y   + (size_t)NT * DIM;

  embed_kernel<<<1024, 256, 0, stream>>>(tokens, emb, pos, x);

  for (int l = 0; l < LAY; l++) {
    ln_kernel<float><<<NT, 256, 0, stream>>>(x, ln1_w + l * DIM, ln1_b + l * DIM, h);
    gemm_kernel<0, false, false><<<dim3(3 * DIM / BN, NT / BM), 256, 0, stream>>>(
        h, qkv_w + (size_t)l * DIM * 3 * DIM, qkv_b + (size_t)l * 3 * DIM,
        nullptr, qkv, NT, 3 * DIM, DIM);
    attn_kernel<float><<<BB * NH * TT, 256, 0, stream>>>(qkv, y);
    gemm_kernel<0, false, true><<<dim3(DIM / BN, NT / BM), 256, 0, stream>>>(
        y, proj_w + (size_t)l * DIM * DIM, proj_b + (size_t)l * DIM,
        x, x, NT, DIM, DIM);
    ln_kernel<float><<<NT, 256, 0, stream>>>(x, ln2_w + l * DIM, ln2_b + l * DIM, h);
    gemm_kernel<1, false, false><<<dim3(FF / BN, NT / BM), 256, 0, stream>>>(
        h, ff1_w + (size_t)l * DIM * FF, ff1_b + (size_t)l * FF,
        nullptr, ffh, NT, FF, DIM);
    gemm_kernel<0, false, true><<<dim3(DIM / BN, NT / BM), 256, 0, stream>>>(
        ffh, ff2_w + (size_t)l * FF * DIM, ff2_b + (size_t)l * DIM,
        x, x, NT, DIM, FF);
  }

  ln_kernel<float><<<NT, 256, 0, stream>>>(x, lnf_w, lnf_b, h);
  gemm_kernel<0, true, false><<<dim3(VOC / BN, NT / BM), 256, 0, stream>>>(
      h, emb, nullptr, nullptr, out, NT, VOC, DIM);
}